// Round 8
// baseline (309.626 us; speedup 1.0000x reference)
//
#include <hip/hip_runtime.h>

// DualBiPlane R8: XCD-pinned bin processing in the interp kernels.
//
// R7 = 193 us. Remaining fat: interp plane fetch ~8 x 41 MB because blocks
// round-robin over XCDs and every XCD sweeps every bin. Fix: bin k is
// processed ONLY by blocks with blockIdx&7 == k&7 (dispatch round-robin ->
// those land on one XCD). Each XCD holds its 2 bins (~2.6 MB) in L2; plane
// bytes are fetched from HBM once total. Records nt-loaded, output
// nt-stored so bins stay resident.
//
// Pipeline: k_conv x2 (f32->fp16, + hist zero) -> k_hist -> k_scan ->
// k_scatter (8B records binned by (m, i>>7)) -> k_interp_xcd x2.

typedef float f32x4 __attribute__((ext_vector_type(4)));
typedef _Float16 f16;
typedef f16 f16x4 __attribute__((ext_vector_type(4)));
typedef f16 f16x8 __attribute__((ext_vector_type(8)));
typedef unsigned int u32;
typedef unsigned long long u64;

constexpr int RES = 400;
constexpr int LCH = 16;
constexpr long long PLANE_STRIDE = (long long)RES * RES * LCH;   // elems per m
constexpr long long PLANE_ELEMS  = 4 * PLANE_STRIDE;             // per family

constexpr int NSLICE = 4;             // i1 >> 7
constexpr int BINS_F = 4 * NSLICE;    // 16 bins per family
constexpr int NBINS  = 2 * BINS_F;    // 32 total (A: 0..15, B: 16..31)
constexpr int PTS_PER_BLOCK = 1024;   // 256 threads x 4 points
constexpr int INTERP_BLOCKS = 2048;   // multiple of 8

constexpr size_t PLANES_BYTES = (size_t)(2 * PLANE_ELEMS) * sizeof(f16); // 40.96 MB

__device__ __forceinline__ float edge(float f) {
    return (f == (float)RES) ? (float)(RES - 1) : f;
}

// quantize coords to 11-bit fixed point fraction; qi < 2^20
__device__ __forceinline__ u32 quant(float f) { return (u32)(edge(f) * 2048.0f); }

__device__ __forceinline__ u64 pack_rec(u32 qi, u32 qj, int p, int m) {
    return (u64)qi | ((u64)qj << 20) | ((u64)((u32)p | ((u32)m << 21)) << 40);
}

// ---------------- conv: f32 plane -> fp16 plane (+ zero hist) ----------------
__global__ __launch_bounds__(256) void k_conv(
    const float* __restrict__ src, f16* __restrict__ dst, long long n,
    u32* __restrict__ histG)
{
    if (blockIdx.x == 0 && threadIdx.x < NBINS) histG[threadIdx.x] = 0u;
    long long i = ((long long)blockIdx.x * 256 + threadIdx.x) * 8;
    if (i >= n) return;
    f32x4 a, b;
    a.x = __builtin_nontemporal_load(src + i);
    a.y = __builtin_nontemporal_load(src + i + 1);
    a.z = __builtin_nontemporal_load(src + i + 2);
    a.w = __builtin_nontemporal_load(src + i + 3);
    b.x = __builtin_nontemporal_load(src + i + 4);
    b.y = __builtin_nontemporal_load(src + i + 5);
    b.z = __builtin_nontemporal_load(src + i + 6);
    b.w = __builtin_nontemporal_load(src + i + 7);
    f16x8 r;
    r[0] = (f16)a.x; r[1] = (f16)a.y; r[2] = (f16)a.z; r[3] = (f16)a.w;
    r[4] = (f16)b.x; r[5] = (f16)b.y; r[6] = (f16)b.z; r[7] = (f16)b.w;
    *reinterpret_cast<f16x8*>(dst + i) = r;
}

// ---------------- hist ----------------
__global__ __launch_bounds__(256) void k_hist(
    const int* __restrict__ mArr, const float* __restrict__ h,
    const float* __restrict__ u,
    u32* __restrict__ histG, int N)
{
    __shared__ u32 lh[NBINS];
    if (threadIdx.x < NBINS) lh[threadIdx.x] = 0;
    __syncthreads();
    int base = blockIdx.x * PTS_PER_BLOCK;
    #pragma unroll
    for (int k = 0; k < 4; ++k) {
        int p = base + threadIdx.x + k * 256;
        if (p < N) {
            int m = mArr[p];
            float hx = h[2ll * p];
            u32 qi = quant((hx + 1.0f) * 0.5f * (float)RES);
            atomicAdd(&lh[m * NSLICE + (qi >> 18)], 1u);
            u32 gi = quant(u[p] * (float)RES);
            atomicAdd(&lh[BINS_F + m * NSLICE + (gi >> 18)], 1u);
        }
    }
    __syncthreads();
    if (threadIdx.x < NBINS) atomicAdd(&histG[threadIdx.x], lh[threadIdx.x]);
}

// ---------------- scan: 32 bins, two independent prefix groups ----------------
__global__ void k_scan(const u32* __restrict__ histG, u32* __restrict__ cursor)
{
    if (threadIdx.x == 0) {
        u32 off = 0;
        for (int b = 0; b < BINS_F; ++b) { cursor[b] = off; off += histG[b]; }
        off = 0;
        for (int b = BINS_F; b < NBINS; ++b) { cursor[b] = off; off += histG[b]; }
    }
}

// ---------------- scatter ----------------
__global__ __launch_bounds__(256) void k_scatter(
    const int* __restrict__ mArr, const float* __restrict__ h,
    const float* __restrict__ u, const float* __restrict__ v,
    u32* __restrict__ cursor, u64* __restrict__ recA, u64* __restrict__ recB,
    int N)
{
    __shared__ u32 lh[NBINS];
    __shared__ u32 lbase[NBINS];
    int tid = threadIdx.x;
    if (tid < NBINS) lh[tid] = 0;
    __syncthreads();

    u64 ra[4], rb[4];
    int bina[4], binb[4];
    u32 la[4], lb[4];
    bool val[4];
    int base = blockIdx.x * PTS_PER_BLOCK;
    #pragma unroll
    for (int k = 0; k < 4; ++k) {
        int p = base + tid + k * 256;
        val[k] = (p < N);
        if (val[k]) {
            int m = mArr[p];
            float hx = h[2ll * p], hy = h[2ll * p + 1];
            u32 qi = quant((hx + 1.0f) * 0.5f * (float)RES);
            u32 qj = quant((hy + 1.0f) * 0.5f * (float)RES);
            ra[k] = pack_rec(qi, qj, p, m);
            bina[k] = m * NSLICE + (int)(qi >> 18);
            la[k] = atomicAdd(&lh[bina[k]], 1u);
            u32 gi = quant(u[p] * (float)RES);
            u32 gj = quant(v[p] * (float)RES);
            rb[k] = pack_rec(gi, gj, p, m);
            binb[k] = BINS_F + m * NSLICE + (int)(gi >> 18);
            lb[k] = atomicAdd(&lh[binb[k]], 1u);
        }
    }
    __syncthreads();
    if (tid < NBINS) lbase[tid] = atomicAdd(&cursor[tid], lh[tid]);
    __syncthreads();
    #pragma unroll
    for (int k = 0; k < 4; ++k) {
        if (val[k]) {
            recA[lbase[bina[k]] + la[k]] = ra[k];
            recB[lbase[binb[k]] + lb[k]] = rb[k];
        }
    }
}

// ---------------- interp, XCD-pinned: bin k handled by blocks with b&7==k&7 ----
// After scatter, cursor[k] = bin end; histG[k] = bin count.
__global__ __launch_bounds__(256) void k_interp_xcd(
    const u64* __restrict__ rec, const f16* __restrict__ F,
    const u32* __restrict__ histG, const u32* __restrict__ cursor,
    int binBase, float* __restrict__ out, int halfOfs)
{
    int x = blockIdx.x & 7;           // XCD slot
    int g = blockIdx.x >> 3;          // local block index within slot
    int G = gridDim.x >> 3;           // blocks per slot
    for (int kb = x; kb < BINS_F; kb += 8) {
        int k = binBase + kb;
        u32 cnt = histG[k];
        u32 start = cursor[k] - cnt;
        long long items = (long long)cnt * 4;
        long long per = (items + G - 1) / G;
        long long lo = (long long)g * per;
        long long hi = lo + per; if (hi > items) hi = items;
        for (long long it = lo + threadIdx.x; it < hi; it += 256) {
            int q = (int)(it >> 2);
            int c = (int)(it & 3);
            u64 r = __builtin_nontemporal_load(rec + start + q);
            u32 qi = (u32)(r & 0xFFFFFu);
            u32 qj = (u32)((r >> 20) & 0xFFFFFu);
            u32 pm = (u32)(r >> 40);
            int p = (int)(pm & 0x1FFFFFu);
            int m = (int)(pm >> 21);

            int i1 = (int)(qi >> 11), j1 = (int)(qj >> 11);
            float ir = (float)(qi & 2047u) * (1.0f / 2048.0f);
            float jr = (float)(qj & 2047u) * (1.0f / 2048.0f);
            int i2 = (i1 + 1 == RES) ? 0 : i1 + 1;
            int j2 = (j1 + 1 == RES) ? 0 : j1 + 1;

            const f16* __restrict__ Fb = F + (long long)m * PLANE_STRIDE + c * 4;
            f16x4 h00 = *reinterpret_cast<const f16x4*>(Fb + (i1 * RES + j1) * LCH);
            f16x4 h10 = *reinterpret_cast<const f16x4*>(Fb + (i2 * RES + j1) * LCH);
            f16x4 h01 = *reinterpret_cast<const f16x4*>(Fb + (i1 * RES + j2) * LCH);
            f16x4 h11 = *reinterpret_cast<const f16x4*>(Fb + (i2 * RES + j2) * LCH);

            float omi = 1.0f - ir, omj = 1.0f - jr;
            f32x4 res;
            #pragma unroll
            for (int kk = 0; kk < 4; ++kk) {
                float g00 = (float)h00[kk], g10 = (float)h10[kk];
                float g01 = (float)h01[kk], g11 = (float)h11[kk];
                res[kk] = (g00 * omi + g10 * ir) * omj + (g01 * omi + g11 * ir) * jr;
            }
            __builtin_nontemporal_store(res,
                reinterpret_cast<f32x4*>(out + (long long)p * 32 + halfOfs + c * 4));
        }
    }
}

// ---------------- fallback: fp16 unsorted ----------------
__global__ __launch_bounds__(256) void dualbiplane_f16(
    const int* __restrict__ mArr, const float* __restrict__ h,
    const float* __restrict__ u, const float* __restrict__ v,
    const f16* __restrict__ Fxy, const f16* __restrict__ Fuv,
    float* __restrict__ out, int N)
{
    long long t = (long long)blockIdx.x * blockDim.x + threadIdx.x;
    int p = (int)(t >> 3);
    if (p >= N) return;
    int sub = (int)(t & 7);
    int mi = __builtin_nontemporal_load(mArr + p);
    float fi, fj;
    const f16* __restrict__ F;
    if (sub < 4) {
        fi = edge((__builtin_nontemporal_load(h + 2ll * p) + 1.0f) * 0.5f * (float)RES);
        fj = edge((__builtin_nontemporal_load(h + 2ll * p + 1) + 1.0f) * 0.5f * (float)RES);
        F = Fxy;
    } else {
        fi = edge(__builtin_nontemporal_load(u + p) * (float)RES);
        fj = edge(__builtin_nontemporal_load(v + p) * (float)RES);
        F = Fuv;
    }
    int i1 = (int)fi, j1 = (int)fj;
    float ir = fi - (float)i1, jr = fj - (float)j1;
    int i2 = (i1 + 1 == RES) ? 0 : i1 + 1;
    int j2 = (j1 + 1 == RES) ? 0 : j1 + 1;
    int c = (sub & 3) * 4;
    const f16* __restrict__ Fb = F + (long long)mi * PLANE_STRIDE + c;
    f16x4 h00 = *reinterpret_cast<const f16x4*>(Fb + (i1 * RES + j1) * LCH);
    f16x4 h10 = *reinterpret_cast<const f16x4*>(Fb + (i2 * RES + j1) * LCH);
    f16x4 h01 = *reinterpret_cast<const f16x4*>(Fb + (i1 * RES + j2) * LCH);
    f16x4 h11 = *reinterpret_cast<const f16x4*>(Fb + (i2 * RES + j2) * LCH);
    float omi = 1.0f - ir, omj = 1.0f - jr;
    f32x4 res;
    #pragma unroll
    for (int k = 0; k < 4; ++k) {
        float g00 = (float)h00[k], g10 = (float)h10[k];
        float g01 = (float)h01[k], g11 = (float)h11[k];
        res[k] = (g00 * omi + g10 * ir) * omj + (g01 * omi + g11 * ir) * jr;
    }
    __builtin_nontemporal_store(res, reinterpret_cast<f32x4*>(out + t * 4));
}

// ---------------- fallback: f32 simple ----------------
__global__ __launch_bounds__(256) void dualbiplane_simple(
    const int* __restrict__ mArr, const float* __restrict__ h,
    const float* __restrict__ u, const float* __restrict__ v,
    const float* __restrict__ Fxy, const float* __restrict__ Fuv,
    float* __restrict__ out, int N)
{
    long long t = (long long)blockIdx.x * blockDim.x + threadIdx.x;
    int p = (int)(t >> 3);
    if (p >= N) return;
    int sub = (int)(t & 7);
    int mi = mArr[p];
    float fi, fj;
    const float* __restrict__ F;
    if (sub < 4) {
        fi = edge((h[2ll * p] + 1.0f) * 0.5f * (float)RES);
        fj = edge((h[2ll * p + 1] + 1.0f) * 0.5f * (float)RES);
        F = Fxy;
    } else {
        fi = edge(u[p] * (float)RES);
        fj = edge(v[p] * (float)RES);
        F = Fuv;
    }
    int i1 = (int)fi, j1 = (int)fj;
    float ir = fi - (float)i1, jr = fj - (float)j1;
    int i2 = (i1 + 1 == RES) ? 0 : i1 + 1;
    int j2 = (j1 + 1 == RES) ? 0 : j1 + 1;
    int c = (sub & 3) * 4;
    const float* __restrict__ Fb = F + (long long)mi * PLANE_STRIDE + c;
    f32x4 g00 = *reinterpret_cast<const f32x4*>(Fb + (i1 * RES + j1) * LCH);
    f32x4 g10 = *reinterpret_cast<const f32x4*>(Fb + (i2 * RES + j1) * LCH);
    f32x4 g01 = *reinterpret_cast<const f32x4*>(Fb + (i1 * RES + j2) * LCH);
    f32x4 g11 = *reinterpret_cast<const f32x4*>(Fb + (i2 * RES + j2) * LCH);
    float omi = 1.0f - ir, omj = 1.0f - jr;
    f32x4 res = (g00 * omi + g10 * ir) * omj + (g01 * omi + g11 * ir) * jr;
    __builtin_nontemporal_store(res, reinterpret_cast<f32x4*>(out + t * 4));
}

extern "C" void kernel_launch(void* const* d_in, const int* in_sizes, int n_in,
                              void* d_out, int out_size, void* d_ws, size_t ws_size,
                              hipStream_t stream)
{
    const int*   m   = (const int*)d_in[0];
    const float* h   = (const float*)d_in[1];
    const float* u   = (const float*)d_in[2];
    const float* v   = (const float*)d_in[3];
    const float* Fxy = (const float*)d_in[4];
    const float* Fuv = (const float*)d_in[5];
    float* out = (float*)d_out;
    int N = in_sizes[0];

    size_t recBytes = (size_t)N * 8;
    size_t offRecA  = PLANES_BYTES;
    size_t offRecB  = offRecA + recBytes;
    size_t offHist  = offRecB + recBytes;
    size_t offCur   = offHist + NBINS * 4;
    size_t needFull = offCur + NBINS * 4;

    if (ws_size >= needFull) {
        char* ws = (char*)d_ws;
        f16*  Fxy16  = (f16*)ws;
        f16*  Fuv16  = Fxy16 + PLANE_ELEMS;
        u64*  recA   = (u64*)(ws + offRecA);
        u64*  recB   = (u64*)(ws + offRecB);
        u32*  histG  = (u32*)(ws + offHist);
        u32*  cursor = (u32*)(ws + offCur);

        unsigned convBlocks = (unsigned)((PLANE_ELEMS / 8 + 255) / 256);
        k_conv<<<convBlocks, 256, 0, stream>>>(Fxy, Fxy16, PLANE_ELEMS, histG);
        k_conv<<<convBlocks, 256, 0, stream>>>(Fuv, Fuv16, PLANE_ELEMS, histG);

        unsigned nb = (unsigned)((N + PTS_PER_BLOCK - 1) / PTS_PER_BLOCK);
        k_hist<<<nb, 256, 0, stream>>>(m, h, u, histG, N);
        k_scan<<<1, 64, 0, stream>>>(histG, cursor);
        k_scatter<<<nb, 256, 0, stream>>>(m, h, u, v, cursor, recA, recB, N);

        k_interp_xcd<<<INTERP_BLOCKS, 256, 0, stream>>>(
            recA, Fxy16, histG, cursor, 0,      out, 0);
        k_interp_xcd<<<INTERP_BLOCKS, 256, 0, stream>>>(
            recB, Fuv16, histG, cursor, BINS_F, out, 16);
    } else if (ws_size >= PLANES_BYTES) {
        f16* Fxy16 = (f16*)d_ws;
        f16* Fuv16 = Fxy16 + PLANE_ELEMS;
        // k_conv's hist-zero needs a target; d_out[0..31] is safe because
        // dualbiplane_f16 later overwrites every d_out element.
        u32* dummy = (u32*)out;
        unsigned convBlocks = (unsigned)((PLANE_ELEMS / 8 + 255) / 256);
        k_conv<<<convBlocks, 256, 0, stream>>>(Fxy, Fxy16, PLANE_ELEMS, dummy);
        k_conv<<<convBlocks, 256, 0, stream>>>(Fuv, Fuv16, PLANE_ELEMS, dummy);
        long long total = (long long)N * 8;
        dualbiplane_f16<<<(unsigned)((total + 255) / 256), 256, 0, stream>>>(
            m, h, u, v, Fxy16, Fuv16, out, N);
    } else {
        long long total = (long long)N * 8;
        dualbiplane_simple<<<(unsigned)((total + 255) / 256), 256, 0, stream>>>(
            m, h, u, v, Fxy, Fuv, out, N);
    }
}

// Round 9
// 187.339 us; speedup vs baseline: 1.6528x; 1.6528x over previous
//
#include <hip/hip_runtime.h>

// DualBiPlane R9: revert R8's XCD pinning (regressed: uneven bins + broke
// dispatch-order temporal convergence). R7 structure + three safe fixes:
//   1. even bin slices: slice = i1/100 (4 slices x 100 rows, 1.64 MB/bin)
//   2. hist fused into conv2's launch (conv1 zeroes histG)
//   3. single merged interp kernel for both families (branchless via
//      contiguous rec[] and plane[] layouts)
// Pipeline: k_conv(Fxy,+zero) -> k_conv_hist(Fuv,+hist) -> k_scan ->
// k_scatter -> k_interp2.

typedef float f32x4 __attribute__((ext_vector_type(4)));
typedef _Float16 f16;
typedef f16 f16x4 __attribute__((ext_vector_type(4)));
typedef f16 f16x8 __attribute__((ext_vector_type(8)));
typedef unsigned int u32;
typedef unsigned long long u64;

constexpr int RES = 400;
constexpr int LCH = 16;
constexpr long long PLANE_STRIDE = (long long)RES * RES * LCH;   // elems per m
constexpr long long PLANE_ELEMS  = 4 * PLANE_STRIDE;             // per family

constexpr int NSLICE = 4;             // i1/100 -> even 100-row slices
constexpr int BINS_F = 4 * NSLICE;    // 16 bins per family
constexpr int NBINS  = 2 * BINS_F;    // 32 total (A: 0..15, B: 16..31)
constexpr int PTS_PER_BLOCK = 1024;   // 256 threads x 4 points

constexpr size_t PLANES_BYTES = (size_t)(2 * PLANE_ELEMS) * sizeof(f16); // 40.96 MB

__device__ __forceinline__ float edge(float f) {
    return (f == (float)RES) ? (float)(RES - 1) : f;
}

// quantize coords to 11-bit fixed point fraction; qi < 2^20
__device__ __forceinline__ u32 quant(float f) { return (u32)(edge(f) * 2048.0f); }

// slice = i1/100 for i1 in [0,400)  (41/4096 approximates 1/100 exactly here)
__device__ __forceinline__ int slice_of(u32 qi) {
    return (int)(((qi >> 11) * 41u) >> 12);
}

__device__ __forceinline__ u64 pack_rec(u32 qi, u32 qj, int p, int m) {
    return (u64)qi | ((u64)qj << 20) | ((u64)((u32)p | ((u32)m << 21)) << 40);
}

// ---------------- conv1: f32 plane -> fp16 plane, + zero hist ----------------
__global__ __launch_bounds__(256) void k_conv(
    const float* __restrict__ src, f16* __restrict__ dst, long long n,
    u32* __restrict__ histG)
{
    if (blockIdx.x == 0 && threadIdx.x < NBINS) histG[threadIdx.x] = 0u;
    long long i = ((long long)blockIdx.x * 256 + threadIdx.x) * 8;
    if (i >= n) return;
    f32x4 a, b;
    a.x = __builtin_nontemporal_load(src + i);
    a.y = __builtin_nontemporal_load(src + i + 1);
    a.z = __builtin_nontemporal_load(src + i + 2);
    a.w = __builtin_nontemporal_load(src + i + 3);
    b.x = __builtin_nontemporal_load(src + i + 4);
    b.y = __builtin_nontemporal_load(src + i + 5);
    b.z = __builtin_nontemporal_load(src + i + 6);
    b.w = __builtin_nontemporal_load(src + i + 7);
    f16x8 r;
    r[0] = (f16)a.x; r[1] = (f16)a.y; r[2] = (f16)a.z; r[3] = (f16)a.w;
    r[4] = (f16)b.x; r[5] = (f16)b.y; r[6] = (f16)b.z; r[7] = (f16)b.w;
    *reinterpret_cast<f16x8*>(dst + i) = r;
}

// ------------- conv2: convert Fuv AND histogram (extra blocks) -------------
__global__ __launch_bounds__(256) void k_conv_hist(
    const float* __restrict__ src, f16* __restrict__ dst, long long n,
    unsigned convBlocks,
    const int* __restrict__ mArr, const float* __restrict__ h,
    const float* __restrict__ u,
    u32* __restrict__ histG, int N)
{
    if (blockIdx.x < convBlocks) {
        long long i = ((long long)blockIdx.x * 256 + threadIdx.x) * 8;
        if (i >= n) return;
        f32x4 a, b;
        a.x = __builtin_nontemporal_load(src + i);
        a.y = __builtin_nontemporal_load(src + i + 1);
        a.z = __builtin_nontemporal_load(src + i + 2);
        a.w = __builtin_nontemporal_load(src + i + 3);
        b.x = __builtin_nontemporal_load(src + i + 4);
        b.y = __builtin_nontemporal_load(src + i + 5);
        b.z = __builtin_nontemporal_load(src + i + 6);
        b.w = __builtin_nontemporal_load(src + i + 7);
        f16x8 r;
        r[0] = (f16)a.x; r[1] = (f16)a.y; r[2] = (f16)a.z; r[3] = (f16)a.w;
        r[4] = (f16)b.x; r[5] = (f16)b.y; r[6] = (f16)b.z; r[7] = (f16)b.w;
        *reinterpret_cast<f16x8*>(dst + i) = r;
        return;
    }
    // histogram blocks
    __shared__ u32 lh[NBINS];
    if (threadIdx.x < NBINS) lh[threadIdx.x] = 0;
    __syncthreads();
    int base = (int)(blockIdx.x - convBlocks) * PTS_PER_BLOCK;
    #pragma unroll
    for (int k = 0; k < 4; ++k) {
        int p = base + threadIdx.x + k * 256;
        if (p < N) {
            int m = mArr[p];
            u32 qi = quant((h[2ll * p] + 1.0f) * 0.5f * (float)RES);
            atomicAdd(&lh[m * NSLICE + slice_of(qi)], 1u);
            u32 gi = quant(u[p] * (float)RES);
            atomicAdd(&lh[BINS_F + m * NSLICE + slice_of(gi)], 1u);
        }
    }
    __syncthreads();
    if (threadIdx.x < NBINS) atomicAdd(&histG[threadIdx.x], lh[threadIdx.x]);
}

// ---------------- scan: 32 bins, two independent prefix groups ----------------
__global__ void k_scan(const u32* __restrict__ histG, u32* __restrict__ cursor)
{
    if (threadIdx.x == 0) {
        u32 off = 0;
        for (int b = 0; b < BINS_F; ++b) { cursor[b] = off; off += histG[b]; }
        off = 0;
        for (int b = BINS_F; b < NBINS; ++b) { cursor[b] = off; off += histG[b]; }
    }
}

// ---------------- scatter ----------------
__global__ __launch_bounds__(256) void k_scatter(
    const int* __restrict__ mArr, const float* __restrict__ h,
    const float* __restrict__ u, const float* __restrict__ v,
    u32* __restrict__ cursor, u64* __restrict__ recA, u64* __restrict__ recB,
    int N)
{
    __shared__ u32 lh[NBINS];
    __shared__ u32 lbase[NBINS];
    int tid = threadIdx.x;
    if (tid < NBINS) lh[tid] = 0;
    __syncthreads();

    u64 ra[4], rb[4];
    int bina[4], binb[4];
    u32 la[4], lb[4];
    bool val[4];
    int base = blockIdx.x * PTS_PER_BLOCK;
    #pragma unroll
    for (int k = 0; k < 4; ++k) {
        int p = base + tid + k * 256;
        val[k] = (p < N);
        if (val[k]) {
            int m = mArr[p];
            float hx = h[2ll * p], hy = h[2ll * p + 1];
            u32 qi = quant((hx + 1.0f) * 0.5f * (float)RES);
            u32 qj = quant((hy + 1.0f) * 0.5f * (float)RES);
            ra[k] = pack_rec(qi, qj, p, m);
            bina[k] = m * NSLICE + slice_of(qi);
            la[k] = atomicAdd(&lh[bina[k]], 1u);
            u32 gi = quant(u[p] * (float)RES);
            u32 gj = quant(v[p] * (float)RES);
            rb[k] = pack_rec(gi, gj, p, m);
            binb[k] = BINS_F + m * NSLICE + slice_of(gi);
            lb[k] = atomicAdd(&lh[binb[k]], 1u);
        }
    }
    __syncthreads();
    if (tid < NBINS) lbase[tid] = atomicAdd(&cursor[tid], lh[tid]);
    __syncthreads();
    #pragma unroll
    for (int k = 0; k < 4; ++k) {
        if (val[k]) {
            recA[lbase[bina[k]] + la[k]] = ra[k];
            recB[lbase[binb[k]] + lb[k]] = rb[k];
        }
    }
}

// ------------- interp, both families in one launch, 4 lanes/record -------------
// rec = recA (recB contiguous at rec+N); Fuv16 contiguous at Fxy16+PLANE_ELEMS.
__global__ __launch_bounds__(256) void k_interp2(
    const u64* __restrict__ rec, const f16* __restrict__ Fxy16,
    float* __restrict__ out, int N)
{
    long long T = (long long)blockIdx.x * 256 + threadIdx.x;
    int q = (int)(T >> 2);
    if (q >= 2 * N) return;
    int c = (int)(T & 3);
    int famB = (q >= N);

    u64 r = __builtin_nontemporal_load(rec + q);
    u32 qi = (u32)(r & 0xFFFFFu);
    u32 qj = (u32)((r >> 20) & 0xFFFFFu);
    u32 pm = (u32)(r >> 40);
    int p = (int)(pm & 0x1FFFFFu);
    int m = (int)(pm >> 21);

    int i1 = (int)(qi >> 11), j1 = (int)(qj >> 11);
    float ir = (float)(qi & 2047u) * (1.0f / 2048.0f);
    float jr = (float)(qj & 2047u) * (1.0f / 2048.0f);
    int i2 = (i1 + 1 == RES) ? 0 : i1 + 1;
    int j2 = (j1 + 1 == RES) ? 0 : j1 + 1;

    const f16* __restrict__ F = Fxy16 + (famB ? PLANE_ELEMS : 0);
    const f16* __restrict__ Fb = F + (long long)m * PLANE_STRIDE + c * 4;
    f16x4 h00 = *reinterpret_cast<const f16x4*>(Fb + (i1 * RES + j1) * LCH);
    f16x4 h10 = *reinterpret_cast<const f16x4*>(Fb + (i2 * RES + j1) * LCH);
    f16x4 h01 = *reinterpret_cast<const f16x4*>(Fb + (i1 * RES + j2) * LCH);
    f16x4 h11 = *reinterpret_cast<const f16x4*>(Fb + (i2 * RES + j2) * LCH);

    float omi = 1.0f - ir, omj = 1.0f - jr;
    f32x4 res;
    #pragma unroll
    for (int k = 0; k < 4; ++k) {
        float g00 = (float)h00[k], g10 = (float)h10[k];
        float g01 = (float)h01[k], g11 = (float)h11[k];
        res[k] = (g00 * omi + g10 * ir) * omj + (g01 * omi + g11 * ir) * jr;
    }
    int halfOfs = famB << 4;
    __builtin_nontemporal_store(res,
        reinterpret_cast<f32x4*>(out + (long long)p * 32 + halfOfs + c * 4));
}

// ---------------- fallback: fp16 unsorted ----------------
__global__ __launch_bounds__(256) void dualbiplane_f16(
    const int* __restrict__ mArr, const float* __restrict__ h,
    const float* __restrict__ u, const float* __restrict__ v,
    const f16* __restrict__ Fxy, const f16* __restrict__ Fuv,
    float* __restrict__ out, int N)
{
    long long t = (long long)blockIdx.x * blockDim.x + threadIdx.x;
    int p = (int)(t >> 3);
    if (p >= N) return;
    int sub = (int)(t & 7);
    int mi = __builtin_nontemporal_load(mArr + p);
    float fi, fj;
    const f16* __restrict__ F;
    if (sub < 4) {
        fi = edge((__builtin_nontemporal_load(h + 2ll * p) + 1.0f) * 0.5f * (float)RES);
        fj = edge((__builtin_nontemporal_load(h + 2ll * p + 1) + 1.0f) * 0.5f * (float)RES);
        F = Fxy;
    } else {
        fi = edge(__builtin_nontemporal_load(u + p) * (float)RES);
        fj = edge(__builtin_nontemporal_load(v + p) * (float)RES);
        F = Fuv;
    }
    int i1 = (int)fi, j1 = (int)fj;
    float ir = fi - (float)i1, jr = fj - (float)j1;
    int i2 = (i1 + 1 == RES) ? 0 : i1 + 1;
    int j2 = (j1 + 1 == RES) ? 0 : j1 + 1;
    int c = (sub & 3) * 4;
    const f16* __restrict__ Fb = F + (long long)mi * PLANE_STRIDE + c;
    f16x4 h00 = *reinterpret_cast<const f16x4*>(Fb + (i1 * RES + j1) * LCH);
    f16x4 h10 = *reinterpret_cast<const f16x4*>(Fb + (i2 * RES + j1) * LCH);
    f16x4 h01 = *reinterpret_cast<const f16x4*>(Fb + (i1 * RES + j2) * LCH);
    f16x4 h11 = *reinterpret_cast<const f16x4*>(Fb + (i2 * RES + j2) * LCH);
    float omi = 1.0f - ir, omj = 1.0f - jr;
    f32x4 res;
    #pragma unroll
    for (int k = 0; k < 4; ++k) {
        float g00 = (float)h00[k], g10 = (float)h10[k];
        float g01 = (float)h01[k], g11 = (float)h11[k];
        res[k] = (g00 * omi + g10 * ir) * omj + (g01 * omi + g11 * ir) * jr;
    }
    __builtin_nontemporal_store(res, reinterpret_cast<f32x4*>(out + t * 4));
}

// ---------------- fallback: f32 simple ----------------
__global__ __launch_bounds__(256) void dualbiplane_simple(
    const int* __restrict__ mArr, const float* __restrict__ h,
    const float* __restrict__ u, const float* __restrict__ v,
    const float* __restrict__ Fxy, const float* __restrict__ Fuv,
    float* __restrict__ out, int N)
{
    long long t = (long long)blockIdx.x * blockDim.x + threadIdx.x;
    int p = (int)(t >> 3);
    if (p >= N) return;
    int sub = (int)(t & 7);
    int mi = mArr[p];
    float fi, fj;
    const float* __restrict__ F;
    if (sub < 4) {
        fi = edge((h[2ll * p] + 1.0f) * 0.5f * (float)RES);
        fj = edge((h[2ll * p + 1] + 1.0f) * 0.5f * (float)RES);
        F = Fxy;
    } else {
        fi = edge(u[p] * (float)RES);
        fj = edge(v[p] * (float)RES);
        F = Fuv;
    }
    int i1 = (int)fi, j1 = (int)fj;
    float ir = fi - (float)i1, jr = fj - (float)j1;
    int i2 = (i1 + 1 == RES) ? 0 : i1 + 1;
    int j2 = (j1 + 1 == RES) ? 0 : j1 + 1;
    int c = (sub & 3) * 4;
    const float* __restrict__ Fb = F + (long long)mi * PLANE_STRIDE + c;
    f32x4 g00 = *reinterpret_cast<const f32x4*>(Fb + (i1 * RES + j1) * LCH);
    f32x4 g10 = *reinterpret_cast<const f32x4*>(Fb + (i2 * RES + j1) * LCH);
    f32x4 g01 = *reinterpret_cast<const f32x4*>(Fb + (i1 * RES + j2) * LCH);
    f32x4 g11 = *reinterpret_cast<const f32x4*>(Fb + (i2 * RES + j2) * LCH);
    float omi = 1.0f - ir, omj = 1.0f - jr;
    f32x4 res = (g00 * omi + g10 * ir) * omj + (g01 * omi + g11 * ir) * jr;
    __builtin_nontemporal_store(res, reinterpret_cast<f32x4*>(out + t * 4));
}

extern "C" void kernel_launch(void* const* d_in, const int* in_sizes, int n_in,
                              void* d_out, int out_size, void* d_ws, size_t ws_size,
                              hipStream_t stream)
{
    const int*   m   = (const int*)d_in[0];
    const float* h   = (const float*)d_in[1];
    const float* u   = (const float*)d_in[2];
    const float* v   = (const float*)d_in[3];
    const float* Fxy = (const float*)d_in[4];
    const float* Fuv = (const float*)d_in[5];
    float* out = (float*)d_out;
    int N = in_sizes[0];

    size_t recBytes = (size_t)N * 8;
    size_t offRecA  = PLANES_BYTES;
    size_t offRecB  = offRecA + recBytes;
    size_t offHist  = offRecB + recBytes;
    size_t offCur   = offHist + NBINS * 4;
    size_t needFull = offCur + NBINS * 4;

    if (ws_size >= needFull) {
        char* ws = (char*)d_ws;
        f16*  Fxy16  = (f16*)ws;
        f16*  Fuv16  = Fxy16 + PLANE_ELEMS;
        u64*  recA   = (u64*)(ws + offRecA);
        u64*  recB   = (u64*)(ws + offRecB);
        u32*  histG  = (u32*)(ws + offHist);
        u32*  cursor = (u32*)(ws + offCur);

        unsigned convBlocks = (unsigned)((PLANE_ELEMS / 8 + 255) / 256);
        unsigned nb = (unsigned)((N + PTS_PER_BLOCK - 1) / PTS_PER_BLOCK);

        k_conv<<<convBlocks, 256, 0, stream>>>(Fxy, Fxy16, PLANE_ELEMS, histG);
        k_conv_hist<<<convBlocks + nb, 256, 0, stream>>>(
            Fuv, Fuv16, PLANE_ELEMS, convBlocks, m, h, u, histG, N);
        k_scan<<<1, 64, 0, stream>>>(histG, cursor);
        k_scatter<<<nb, 256, 0, stream>>>(m, h, u, v, cursor, recA, recB, N);

        unsigned bi = (unsigned)(((long long)N * 8 + 255) / 256);
        k_interp2<<<bi, 256, 0, stream>>>(recA, Fxy16, out, N);
    } else if (ws_size >= PLANES_BYTES) {
        f16* Fxy16 = (f16*)d_ws;
        f16* Fuv16 = Fxy16 + PLANE_ELEMS;
        // k_conv's hist-zero target: d_out[0..31] is safe (overwritten later).
        u32* dummy = (u32*)out;
        unsigned convBlocks = (unsigned)((PLANE_ELEMS / 8 + 255) / 256);
        k_conv<<<convBlocks, 256, 0, stream>>>(Fxy, Fxy16, PLANE_ELEMS, dummy);
        k_conv<<<convBlocks, 256, 0, stream>>>(Fuv, Fuv16, PLANE_ELEMS, dummy);
        long long total = (long long)N * 8;
        dualbiplane_f16<<<(unsigned)((total + 255) / 256), 256, 0, stream>>>(
            m, h, u, v, Fxy16, Fuv16, out, N);
    } else {
        long long total = (long long)N * 8;
        dualbiplane_simple<<<(unsigned)((total + 255) / 256), 256, 0, stream>>>(
            m, h, u, v, Fxy, Fuv, out, N);
    }
}